// Round 22
// baseline (137.601 us; speedup 1.0000x reference)
//
#include <hip/hip_runtime.h>
#include <hip/hip_bf16.h>
#include <hip/hip_cooperative_groups.h>

namespace cg = cooperative_groups;

#define CFEAT 128
#define NODES 2048
#define NM    219            // 9 deg1 + 45 deg2 + 165 deg3 monomials
#define NSTEP 7              // K padded to 224 = 7*32 (16x16x32 MFMA)

typedef __attribute__((ext_vector_type(8))) short short8;
typedef __attribute__((ext_vector_type(4))) float f32x4;
typedef __attribute__((ext_vector_type(4))) unsigned int uint4v;

__device__ __forceinline__ short f2bf(float x) {
    union { __hip_bfloat16 b; short s; } cv;
    cv.b = __float2bfloat16(x);
    return cv.s;
}

// ---- monomial index -> (deg,i,j,l), i<=j<=l (constexpr) --------------------
struct MIdx { int deg, i, j, l; };
__host__ __device__ constexpr MIdx decode_c(int idx) {
    if (idx < 9) return {1, idx, 0, 0};
    int t = idx - 9;
    for (int i = 0; i < 9; ++i)
        for (int j = i; j < 9; ++j) {
            int cnt = 10 - j;
            if (t < cnt) {
                if (t == 0) return {2, i, j, 0};
                return {3, i, j, j + t - 1};
            }
            t -= cnt;
        }
    return {0, 0, 0, 0};
}

struct KTbl { MIdx v[224]; };
__host__ __device__ constexpr KTbl gen_ktbl() {
    KTbl t{};
    for (int k = 0; k < 224; ++k)
        t.v[k] = (k < NM) ? decode_c(k) : MIdx{0, 0, 0, 0};
    return t;
}
__device__ constexpr KTbl KT = gen_ktbl();

template<int K>
__device__ __forceinline__ float mono_val_t(const float a[9]) {
    if constexpr (K >= NM) return 0.f;
    else {
        constexpr MIdx d = decode_c(K);
        if constexpr (d.deg == 1) return a[d.i];
        else if constexpr (d.deg == 2) return a[d.i] * a[d.j];
        else return a[d.i] * a[d.j] * a[d.l];
    }
}

// pack two monomials to 2xbf16 in one dword (r14/r18 best-measured form)
template<int KB, int E2>
__device__ __forceinline__ unsigned pack2(const float a[9]) {
    union { struct { short lo, hi; } p; unsigned u; } cv;
    cv.p.lo = f2bf(mono_val_t<KB + 2 * E2>(a));
    cv.p.hi = f2bf(mono_val_t<KB + 2 * E2 + 1>(a));
    return cv.u;
}
template<int KB>
__device__ __forceinline__ uint4v build_granule(const float a[9]) {
    return uint4v{pack2<KB,0>(a), pack2<KB,1>(a), pack2<KB,2>(a), pack2<KB,3>(a)};
}

// ---- hot step (r6 structure) -----------------------------------------------
template<int S>
__device__ __forceinline__ void do_step(const float a[9], char* wrbase, const char* rdbase,
                                        const short8 bfrag[NSTEP], f32x4 acc[4])
{
    const uint4v g0 = build_granule<S * 32 +  0>(a);
    const uint4v g1 = build_granule<S * 32 +  8>(a);
    const uint4v g2 = build_granule<S * 32 + 16>(a);
    const uint4v g3 = build_granule<S * 32 + 24>(a);
    *(uint4v*)(wrbase       ) = g0;
    *(uint4v*)(wrbase + 1024) = g1;
    *(uint4v*)(wrbase + 2048) = g2;
    *(uint4v*)(wrbase + 3072) = g3;
    #pragma unroll
    for (int t = 0; t < 4; ++t) {
        short8 af = *(const short8*)(rdbase + t * 256);
        acc[t] = __builtin_amdgcn_mfma_f32_16x16x32_bf16(af, bfrag[S], acc[t], 0, 0, 0);
    }
}

// ---- fused cooperative kernel: prep (blocks 0-111) -> grid.sync -> hot -----
// Wf layout (m-major): short index (((c*NSTEP + s)*16 + m)*32 + kl).
// Prep/hot bodies are r21-verbatim; A-loads issued BEFORE prep so the cold
// HBM fetch overlaps prep's latency-bound gather.
#define SROW 148   // sA row stride in floats (144 used + 4 pad, float4-aligned)
__global__ __launch_bounds__(1024, 1) void symcon_fused(
    const float* __restrict__ A,
    const float* __restrict__ Us1, const float* __restrict__ ws1,
    const float* __restrict__ Us2, const float* __restrict__ ws2,
    const float* __restrict__ Us3, const float* __restrict__ ws3,
    const float* __restrict__ Up1, const float* __restrict__ wp1,
    const float* __restrict__ Up2, const float* __restrict__ wp2,
    const float* __restrict__ Up3, const float* __restrict__ wp3,
    const float* __restrict__ Ud1, const float* __restrict__ wd1,
    const float* __restrict__ Ud2, const float* __restrict__ wd2,
    const float* __restrict__ Ud3, const float* __restrict__ wd3,
    short* __restrict__ Wf, float* __restrict__ out)
{
    const int bid = blockIdx.x;                 // 0..255
    const int tid = threadIdx.x;
    const int w = tid >> 6, l = tid & 63;       // wave 0..15, lane
    const int p = l & 15, q = l >> 4;
    const int c0 = (bid & 7) * 16;              // hot: 16 adjacent channels
    const int nb = (bid >> 3) * 64;             // hot: 64 nodes

    __shared__ float sA[64 * SROW];                    // 37.9 KB out-staging
    __shared__ __align__(16) char phiAll[16 * 4096];   // 64 KB phi (Urow overlay in prep)

    // ---- issue per-lane A loads NOW (overlap cold fetch with prep) ---------
    const float* Ap = A + ((size_t)(nb + l) * CFEAT + (c0 + w)) * 9;
    float a[9];
    #pragma unroll
    for (int x = 0; x < 9; ++x) a[x] = Ap[x];

    // ---- phase P: prep, r21 body (blocks 0..111 own (mg, s)) ---------------
    if (bid < 112) {
        const int mg = bid / 7;     // 0..15 (9..15 = zero lanes)
        const int s  = bid % 7;

        if (mg >= 9) {
            if (tid < 256) {
                const int c = tid >> 1, h = tid & 1;
                short* dst = Wf + (((size_t)c * NSTEP + s) * 16 + mg) * 32 + h * 16;
                const short8 z{};
                *(short8*)dst = z;
                *(short8*)(dst + 8) = z;
            }
        } else {
            const float *U1, *U2, *U3, *w1, *w2, *w3; int K2, K3, ml;
            if (mg == 0) {
                U1 = Us1; U2 = Us2; U3 = Us3; w1 = ws1; w2 = ws2; w3 = ws3;
                K2 = 2; K3 = 5;  ml = 0;
            } else if (mg < 4) {
                U1 = Up1; U2 = Up2; U3 = Up3; w1 = wp1; w2 = wp2; w3 = wp3;
                K2 = 3; K3 = 8;  ml = mg - 1;
            } else {
                U1 = Ud1; U2 = Ud2; U3 = Ud3; w1 = wd1; w2 = wd2; w3 = wd3;
                K2 = 4; K3 = 10; ml = mg - 4;
            }

            float (*Urow)[16] = (float(*)[16])phiAll;   // 2 KB overlay (dead until hot)

            for (int slot = tid; slot < 512; slot += 1024) {
                const int kl = slot >> 4, kk = slot & 15;
                const int k = s * 32 + kl;
                float v = 0.f;
                if (k < NM) {
                    const MIdx d = KT.v[k];
                    if (d.deg == 1) {
                        if (kk == 0) v = U1[ml * 9 + d.i];
                    } else if (d.deg == 2) {
                        if (kk < K2) {
                            v = U2[((size_t)(ml * 9 + d.i) * 9 + d.j) * K2 + kk];
                            if (d.i != d.j)
                                v += U2[((size_t)(ml * 9 + d.j) * 9 + d.i) * K2 + kk];
                        }
                    } else {
                        if (kk < K3) {
                            const int i = d.i, j = d.j, ll = d.l;
                            const int e0=(i*9+j)*9+ll, e1=(i*9+ll)*9+j, e2=(j*9+i)*9+ll,
                                      e3=(j*9+ll)*9+i, e4=(ll*9+i)*9+j, e5=(ll*9+j)*9+i;
                            const float* B3 = U3 + (size_t)ml * 729 * K3 + kk;
                            v = B3[(size_t)e0 * K3];
                            if (e1 != e0)                                     v += B3[(size_t)e1 * K3];
                            if (e2 != e0 && e2 != e1)                         v += B3[(size_t)e2 * K3];
                            if (e3 != e0 && e3 != e1 && e3 != e2)             v += B3[(size_t)e3 * K3];
                            if (e4 != e0 && e4 != e1 && e4 != e2 && e4 != e3) v += B3[(size_t)e4 * K3];
                            if (e5 != e0 && e5 != e1 && e5 != e2 && e5 != e3 && e5 != e4)
                                                                              v += B3[(size_t)e5 * K3];
                        }
                    }
                }
                Urow[kl][kk] = v;
            }
            __syncthreads();

            if (tid < 256) {
                const int c  = tid & 127;
                const int kb = (tid >> 7) << 4;

                const float wr1 = w1[c];
                float wr2[4], wr3[12];
                #pragma unroll
                for (int kk = 0; kk < 4; ++kk)  wr2[kk] = (kk < K2) ? w2[kk * CFEAT + c] : 0.f;
                #pragma unroll
                for (int kk = 0; kk < 12; ++kk) wr3[kk] = (kk < K3) ? w3[kk * CFEAT + c] : 0.f;

                short8 o0{}, o1{};
                #pragma unroll
                for (int x = 0; x < 16; ++x) {
                    const int kl = kb + x;
                    const int k  = s * 32 + kl;
                    float v = 0.f;
                    if (k < NM) {
                        const MIdx d = KT.v[k];
                        if (d.deg == 1) {
                            v = Urow[kl][0] * wr1;
                        } else if (d.deg == 2) {
                            #pragma unroll
                            for (int kk = 0; kk < 4; ++kk)
                                v = fmaf(Urow[kl][kk], wr2[kk], v);
                        } else {
                            #pragma unroll
                            for (int kk = 0; kk < 12; ++kk)
                                v = fmaf(Urow[kl][kk], wr3[kk], v);
                        }
                    }
                    if (x < 8) o0[x] = f2bf(v); else o1[x - 8] = f2bf(v);
                }
                short* dst = Wf + (((size_t)c * NSTEP + s) * 16 + mg) * 32 + kb;
                *(short8*)dst = o0;
                *(short8*)(dst + 8) = o1;
            }
        }
    }

    // ---- grid-wide barrier: Wf complete & visible --------------------------
    __threadfence();
    cg::this_grid().sync();

    // ---- phase H: hot, r21 body --------------------------------------------
    const short8* Wc = (const short8*)Wf + (size_t)(c0 + w) * NSTEP * 64;
    short8 bfrag[NSTEP];
    #pragma unroll
    for (int s = 0; s < NSTEP; ++s) bfrag[s] = Wc[s * 64 + (l & 15) * 4 + (l >> 4)];

    char* const phiW   = phiAll + w * 4096;
    char* const wrbase = phiW + l * 16;
    const char* const rdbase = phiW + q * 1024 + p * 16;

    f32x4 acc[4];
    #pragma unroll
    for (int t = 0; t < 4; ++t) acc[t] = f32x4{0.f, 0.f, 0.f, 0.f};

    do_step<0>(a, wrbase, rdbase, bfrag, acc);
    do_step<1>(a, wrbase, rdbase, bfrag, acc);
    do_step<2>(a, wrbase, rdbase, bfrag, acc);
    do_step<3>(a, wrbase, rdbase, bfrag, acc);
    do_step<4>(a, wrbase, rdbase, bfrag, acc);
    do_step<5>(a, wrbase, rdbase, bfrag, acc);
    do_step<6>(a, wrbase, rdbase, bfrag, acc);

    // C/D (m89): col = p = m, row = q*4 + reg (node within 16-tile t)
    __syncthreads();   // prep's Urow overlay fully dead; phi reads done
    if (p < 9) {
        #pragma unroll
        for (int t = 0; t < 4; ++t)
            #pragma unroll
            for (int r = 0; r < 4; ++r)
                sA[(t * 16 + q * 4 + r) * SROW + w * 9 + p] = acc[t][r];
    }
    __syncthreads();

    // out-stage: 576B-aligned full-sector runs per node
    const size_t gbase = (size_t)nb * (CFEAT * 9) + (size_t)c0 * 9;
    #pragma unroll
    for (int e = tid; e < 64 * 36; e += 1024) {
        const int n = e / 36, f = e - n * 36;
        const float* src = &sA[n * SROW + f * 4];
        const float4 v{src[0], src[1], src[2], src[3]};
        *(float4*)(out + gbase + (size_t)n * (CFEAT * 9) + f * 4) = v;
    }
}

extern "C" void kernel_launch(void* const* d_in, const int* in_sizes, int n_in,
                              void* d_out, int out_size, void* d_ws, size_t ws_size,
                              hipStream_t stream)
{
    const float* A   = (const float*)d_in[0];
    const float* Us1 = (const float*)d_in[1];  const float* ws1 = (const float*)d_in[2];
    const float* Us2 = (const float*)d_in[3];  const float* ws2 = (const float*)d_in[4];
    const float* Us3 = (const float*)d_in[5];  const float* ws3 = (const float*)d_in[6];
    const float* Up1 = (const float*)d_in[7];  const float* wp1 = (const float*)d_in[8];
    const float* Up2 = (const float*)d_in[9];  const float* wp2 = (const float*)d_in[10];
    const float* Up3 = (const float*)d_in[11]; const float* wp3 = (const float*)d_in[12];
    const float* Ud1 = (const float*)d_in[13]; const float* wd1 = (const float*)d_in[14];
    const float* Ud2 = (const float*)d_in[15]; const float* wd2 = (const float*)d_in[16];
    const float* Ud3 = (const float*)d_in[17]; const float* wd3 = (const float*)d_in[18];
    float* out = (float*)d_out;
    short* Wf  = (short*)d_ws;   // 128*7*16*32 shorts = 1.75 MB

    void* args[] = {
        (void*)&A,
        (void*)&Us1, (void*)&ws1, (void*)&Us2, (void*)&ws2, (void*)&Us3, (void*)&ws3,
        (void*)&Up1, (void*)&wp1, (void*)&Up2, (void*)&wp2, (void*)&Up3, (void*)&wp3,
        (void*)&Ud1, (void*)&wd1, (void*)&Ud2, (void*)&wd2, (void*)&Ud3, (void*)&wd3,
        (void*)&Wf, (void*)&out
    };
    hipLaunchCooperativeKernel((const void*)symcon_fused, dim3(256), dim3(1024),
                               args, 0, stream);
}

// Round 23
// 22.116 us; speedup vs baseline: 6.2218x; 6.2218x over previous
//
#include <hip/hip_runtime.h>
#include <hip/hip_bf16.h>

#define CFEAT 128
#define NODES 2048
#define NM    219            // 9 deg1 + 45 deg2 + 165 deg3 monomials
#define NSTEP 7              // K padded to 224 = 7*32 (16x16x32 MFMA)

typedef __attribute__((ext_vector_type(8))) short short8;
typedef __attribute__((ext_vector_type(4))) float f32x4;
typedef __attribute__((ext_vector_type(4))) unsigned int uint4v;

__device__ __forceinline__ short f2bf(float x) {
    union { __hip_bfloat16 b; short s; } cv;
    cv.b = __float2bfloat16(x);
    return cv.s;
}

// ---- monomial index -> (deg,i,j,l), i<=j<=l (constexpr) --------------------
struct MIdx { int deg, i, j, l; };
__host__ __device__ constexpr MIdx decode_c(int idx) {
    if (idx < 9) return {1, idx, 0, 0};
    int t = idx - 9;
    for (int i = 0; i < 9; ++i)
        for (int j = i; j < 9; ++j) {
            int cnt = 10 - j;
            if (t < cnt) {
                if (t == 0) return {2, i, j, 0};
                return {3, i, j, j + t - 1};
            }
            t -= cnt;
        }
    return {0, 0, 0, 0};
}

struct KTbl { MIdx v[224]; };
__host__ __device__ constexpr KTbl gen_ktbl() {
    KTbl t{};
    for (int k = 0; k < 224; ++k)
        t.v[k] = (k < NM) ? decode_c(k) : MIdx{0, 0, 0, 0};
    return t;
}
__device__ constexpr KTbl KT = gen_ktbl();

template<int K>
__device__ __forceinline__ float mono_val_t(const float a[9]) {
    if constexpr (K >= NM) return 0.f;
    else {
        constexpr MIdx d = decode_c(K);
        if constexpr (d.deg == 1) return a[d.i];
        else if constexpr (d.deg == 2) return a[d.i] * a[d.j];
        else return a[d.i] * a[d.j] * a[d.l];
    }
}

// pack two monomials to 2xbf16 in one dword (r14/r18 best-measured form)
template<int KB, int E2>
__device__ __forceinline__ unsigned pack2(const float a[9]) {
    union { struct { short lo, hi; } p; unsigned u; } cv;
    cv.p.lo = f2bf(mono_val_t<KB + 2 * E2>(a));
    cv.p.hi = f2bf(mono_val_t<KB + 2 * E2 + 1>(a));
    return cv.u;
}
template<int KB>
__device__ __forceinline__ uint4v build_granule(const float a[9]) {
    return uint4v{pack2<KB,0>(a), pack2<KB,1>(a), pack2<KB,2>(a), pack2<KB,3>(a)};
}

// ---- fused prep (r21 structure, 512 threads, zero-fill blocks dropped) -----
// Wf layout (m-major): short index (((c*NSTEP + s)*16 + m)*32 + kl).
// m=9..15 lanes are never written: MFMA column n depends only on B column n,
// and hot discards output columns 9..15 (p<9 guard) -> poison there is inert.
__global__ __launch_bounds__(512) void symcon_prep(
    const float* __restrict__ Us1, const float* __restrict__ ws1,
    const float* __restrict__ Us2, const float* __restrict__ ws2,
    const float* __restrict__ Us3, const float* __restrict__ ws3,
    const float* __restrict__ Up1, const float* __restrict__ wp1,
    const float* __restrict__ Up2, const float* __restrict__ wp2,
    const float* __restrict__ Up3, const float* __restrict__ wp3,
    const float* __restrict__ Ud1, const float* __restrict__ wd1,
    const float* __restrict__ Ud2, const float* __restrict__ wd2,
    const float* __restrict__ Ud3, const float* __restrict__ wd3,
    short* __restrict__ Wf)
{
    const int mg = blockIdx.x;   // 0..8
    const int s  = blockIdx.y;   // 0..6
    const int t  = threadIdx.x;  // 0..511

    const float *U1, *U2, *U3, *w1, *w2, *w3; int K2, K3, ml;
    if (mg == 0) {
        U1 = Us1; U2 = Us2; U3 = Us3; w1 = ws1; w2 = ws2; w3 = ws3;
        K2 = 2; K3 = 5;  ml = 0;
    } else if (mg < 4) {
        U1 = Up1; U2 = Up2; U3 = Up3; w1 = wp1; w2 = wp2; w3 = wp3;
        K2 = 3; K3 = 8;  ml = mg - 1;
    } else {
        U1 = Ud1; U2 = Ud2; U3 = Ud3; w1 = wd1; w2 = wd2; w3 = wd3;
        K2 = 4; K3 = 10; ml = mg - 4;
    }

    __shared__ float Urow[32][16];   // 2 KB

    // ---- phase A: 512 slots (kl, kk), 1 slot/thread (max MLP) --------------
    {
        const int slot = t;
        const int kl = slot >> 4, kk = slot & 15;
        const int k = s * 32 + kl;
        float v = 0.f;
        if (k < NM) {
            const MIdx d = KT.v[k];
            if (d.deg == 1) {
                if (kk == 0) v = U1[ml * 9 + d.i];
            } else if (d.deg == 2) {
                if (kk < K2) {
                    v = U2[((size_t)(ml * 9 + d.i) * 9 + d.j) * K2 + kk];
                    if (d.i != d.j)
                        v += U2[((size_t)(ml * 9 + d.j) * 9 + d.i) * K2 + kk];
                }
            } else {
                if (kk < K3) {
                    const int i = d.i, j = d.j, l = d.l;
                    const int e0=(i*9+j)*9+l, e1=(i*9+l)*9+j, e2=(j*9+i)*9+l,
                              e3=(j*9+l)*9+i, e4=(l*9+i)*9+j, e5=(l*9+j)*9+i;
                    const float* B3 = U3 + (size_t)ml * 729 * K3 + kk;
                    v = B3[(size_t)e0 * K3];
                    if (e1 != e0)                                     v += B3[(size_t)e1 * K3];
                    if (e2 != e0 && e2 != e1)                         v += B3[(size_t)e2 * K3];
                    if (e3 != e0 && e3 != e1 && e3 != e2)             v += B3[(size_t)e3 * K3];
                    if (e4 != e0 && e4 != e1 && e4 != e2 && e4 != e3) v += B3[(size_t)e4 * K3];
                    if (e5 != e0 && e5 != e1 && e5 != e2 && e5 != e3 && e5 != e4)
                                                                      v += B3[(size_t)e5 * K3];
                }
            }
        }
        Urow[kl][kk] = v;
    }
    __syncthreads();

    // ---- phase B: threads 0..255 weight 128 channels -----------------------
    if (t < 256) {
        const int c  = t & 127;
        const int kb = (t >> 7) << 4;

        const float wr1 = w1[c];
        float wr2[4], wr3[12];
        #pragma unroll
        for (int kk = 0; kk < 4; ++kk)  wr2[kk] = (kk < K2) ? w2[kk * CFEAT + c] : 0.f;
        #pragma unroll
        for (int kk = 0; kk < 12; ++kk) wr3[kk] = (kk < K3) ? w3[kk * CFEAT + c] : 0.f;

        short8 o0{}, o1{};
        #pragma unroll
        for (int x = 0; x < 16; ++x) {
            const int kl = kb + x;
            const int k  = s * 32 + kl;
            float v = 0.f;
            if (k < NM) {                       // wave-uniform condition
                const MIdx d = KT.v[k];
                if (d.deg == 1) {
                    v = Urow[kl][0] * wr1;
                } else if (d.deg == 2) {
                    #pragma unroll
                    for (int kk = 0; kk < 4; ++kk)
                        v = fmaf(Urow[kl][kk], wr2[kk], v);   // pads: fmaf(0,0,v)
                } else {
                    #pragma unroll
                    for (int kk = 0; kk < 12; ++kk)
                        v = fmaf(Urow[kl][kk], wr3[kk], v);   // pads: fmaf(0,0,v)
                }
            }
            if (x < 8) o0[x] = f2bf(v); else o1[x - 8] = f2bf(v);
        }
        short* dst = Wf + (((size_t)c * NSTEP + s) * 16 + mg) * 32 + kb;
        *(short8*)dst = o0;
        *(short8*)(dst + 8) = o1;
    }
}

// ---- hot step (r6 structure) -----------------------------------------------
template<int S>
__device__ __forceinline__ void do_step(const float a[9], char* wrbase, const char* rdbase,
                                        const short8 bfrag[NSTEP], f32x4 acc[4])
{
    const uint4v g0 = build_granule<S * 32 +  0>(a);
    const uint4v g1 = build_granule<S * 32 +  8>(a);
    const uint4v g2 = build_granule<S * 32 + 16>(a);
    const uint4v g3 = build_granule<S * 32 + 24>(a);
    *(uint4v*)(wrbase       ) = g0;
    *(uint4v*)(wrbase + 1024) = g1;
    *(uint4v*)(wrbase + 2048) = g2;
    *(uint4v*)(wrbase + 3072) = g3;
    #pragma unroll
    for (int t = 0; t < 4; ++t) {
        short8 af = *(const short8*)(rdbase + t * 256);
        acc[t] = __builtin_amdgcn_mfma_f32_16x16x32_bf16(af, bfrag[S], acc[t], 0, 0, 0);
    }
}

// ---- hot: r21 verbatim (direct per-lane A input, m-major bfrag) ------------
#define SROW 148   // sA row stride in floats (144 used + 4 pad, float4-aligned)
__global__ __launch_bounds__(1024, 1) void symcon_hot(
    const float* __restrict__ A, const short* __restrict__ Wf, float* __restrict__ out)
{
    const int tid = threadIdx.x;
    const int w = tid >> 6, l = tid & 63;       // wave 0..15, lane
    const int p = l & 15, q = l >> 4;
    const int c0 = blockIdx.x * 16;             // 16 adjacent channels per block
    const int nb = blockIdx.y * 64;             // 64 nodes per block

    __shared__ float sA[64 * SROW];                    // 37.9 KB: OUTPUT staging only
    __shared__ __align__(16) char phiAll[16 * 4096];   // 64 KB wave-private phi

    // B fragments: m-major Wf -> lane l reads short8 (l&15)*4 + (l>>4)
    const short8* Wc = (const short8*)Wf + (size_t)(c0 + w) * NSTEP * 64;
    short8 bfrag[NSTEP];
    #pragma unroll
    for (int s = 0; s < NSTEP; ++s) bfrag[s] = Wc[s * 64 + (l & 15) * 4 + (l >> 4)];

    // direct per-lane A load: node nb+l, channel c0+w (36 contiguous bytes)
    const float* Ap = A + ((size_t)(nb + l) * CFEAT + (c0 + w)) * 9;
    float a[9];
    #pragma unroll
    for (int x = 0; x < 9; ++x) a[x] = Ap[x];

    char* const phiW   = phiAll + w * 4096;
    char* const wrbase = phiW + l * 16;
    const char* const rdbase = phiW + q * 1024 + p * 16;

    f32x4 acc[4];
    #pragma unroll
    for (int t = 0; t < 4; ++t) acc[t] = f32x4{0.f, 0.f, 0.f, 0.f};

    do_step<0>(a, wrbase, rdbase, bfrag, acc);
    do_step<1>(a, wrbase, rdbase, bfrag, acc);
    do_step<2>(a, wrbase, rdbase, bfrag, acc);
    do_step<3>(a, wrbase, rdbase, bfrag, acc);
    do_step<4>(a, wrbase, rdbase, bfrag, acc);
    do_step<5>(a, wrbase, rdbase, bfrag, acc);
    do_step<6>(a, wrbase, rdbase, bfrag, acc);

    // C/D (m89): col = p = m, row = q*4 + reg (node within 16-tile t)
    if (p < 9) {
        #pragma unroll
        for (int t = 0; t < 4; ++t)
            #pragma unroll
            for (int r = 0; r < 4; ++r)
                sA[(t * 16 + q * 4 + r) * SROW + w * 9 + p] = acc[t][r];
    }
    __syncthreads();

    // out-stage: 576B-aligned full-sector runs per node
    const size_t gbase = (size_t)nb * (CFEAT * 9) + (size_t)c0 * 9;  // 64B-aligned
    #pragma unroll
    for (int e = tid; e < 64 * 36; e += 1024) {
        const int n = e / 36, f = e - n * 36;
        const float* src = &sA[n * SROW + f * 4];
        const float4 v{src[0], src[1], src[2], src[3]};
        *(float4*)(out + gbase + (size_t)n * (CFEAT * 9) + f * 4) = v;
    }
}

extern "C" void kernel_launch(void* const* d_in, const int* in_sizes, int n_in,
                              void* d_out, int out_size, void* d_ws, size_t ws_size,
                              hipStream_t stream)
{
    const float* A   = (const float*)d_in[0];
    const float* Us1 = (const float*)d_in[1];  const float* ws1 = (const float*)d_in[2];
    const float* Us2 = (const float*)d_in[3];  const float* ws2 = (const float*)d_in[4];
    const float* Us3 = (const float*)d_in[5];  const float* ws3 = (const float*)d_in[6];
    const float* Up1 = (const float*)d_in[7];  const float* wp1 = (const float*)d_in[8];
    const float* Up2 = (const float*)d_in[9];  const float* wp2 = (const float*)d_in[10];
    const float* Up3 = (const float*)d_in[11]; const float* wp3 = (const float*)d_in[12];
    const float* Ud1 = (const float*)d_in[13]; const float* wd1 = (const float*)d_in[14];
    const float* Ud2 = (const float*)d_in[15]; const float* wd2 = (const float*)d_in[16];
    const float* Ud3 = (const float*)d_in[17]; const float* wd3 = (const float*)d_in[18];
    float* out = (float*)d_out;
    short* Wf  = (short*)d_ws;   // 128*7*16*32 shorts = 1.75 MB

    symcon_prep<<<dim3(9, NSTEP), 512, 0, stream>>>(
        Us1, ws1, Us2, ws2, Us3, ws3, Up1, wp1, Up2, wp2, Up3, wp3,
        Ud1, wd1, Ud2, wd2, Ud3, wd3, Wf);

    symcon_hot<<<dim3(CFEAT / 16, NODES / 64), 1024, 0, stream>>>(A, Wf, out);
}